// Round 4
// baseline (83.180 us; speedup 1.0000x reference)
//
#include <hip/hip_runtime.h>
#include <math.h>

// GRNN Kalman scan, R10: R9 minus the output LDS staging.
// R9 post-mortem: removing ~900 VALU + 72 shfl + 2 barriers gained only
// 1.1us -> dur_us is dominated by harness overhead (44us 256MiB d_ws poison
// fill + reset memsets + launch). Kernel itself ~5-10us. Remaining lever:
// phase D's h-values are per-thread contiguous (thread c owns bytes
// [128c,128c+128) of dy_hat) -> store 8x float4 (h,0,h,0) directly; the
// wave's stores fully tile its 8KB span so L2 write-combining makes full
// lines. Deletes 16 LDS writes + 8 LDS reads + final barrier; LDS 16.5KB->96B.
// Fixed-point predictor cap REJECTED: vp's slow mode (lambda ~ -1.24) is not
// converged by t=1.5; residual ~0.075 would risk absmax for ~0.3us.
// Output values bit-identical to R9 -> absmax stays 0.0078.

constexpr int T = 4096;
constexpr int B = 512;
constexpr int CH = 16;       // steps per chunk
constexpr int NC = T / CH;   // 256 chunks

__global__ __launch_bounds__(256, 2) void grnn_fused(
    const float* __restrict__ dy,
    const float* __restrict__ state0,
    const float* __restrict__ omega_p,
    float* __restrict__ out)
{
    __shared__ float wtotX[4][6];    // phase-C scan wave totals (96 B)
    const int b  = blockIdx.x;
    const int c  = threadIdx.x;
    const int l  = c & 63;
    const int wv = c >> 6;

    const float DT = 0.001f;
    const float w  = omega_p[0];
    const float k1 = 1.0f + DT * (-0.3f);
    const float k2 = DT * 2.0f * w;
    const float k3 = DT * 1.65f;
    const float k4 = DT * 2.88f;
    const float kw = DT * w;
    const float kA = 1.0f + DT * (-0.15f);
    const float cc = 1.69705627484771f;
    const float kcDT = cc * DT;
    const float nk4 = -k4;
    const float w2c = 2.0f * w;

    // ---- per-thread dy loads: thread c owns steps [16c, 16c+16) ----
    // dy0 at those steps = dyb[32c + 2j], a contiguous 128 B span.
    const float* dyb = dy + (size_t)b * (T * 2);
    float4 dreg[8];
    #pragma unroll
    for (int k = 0; k < 8; ++k)
        dreg[k] = *(const float4*)(dyb + 32 * c + 4 * k);

    // ---- RK2 (Heun) predictor: 32 coarse (dt=128DT) + (c&7) medium (16DT) ----
    float S0, S1, S2;
    {
        const int Q = c >> 3, r = c & 7;
        float vx = state0[2], vp = state0[3], cx = state0[4];
        S0 = vx; S1 = vp; S2 = cx;
        const float dtC = 128.0f * DT, hC = 64.0f * DT;
        for (int i = 0; i < 32; ++i) {
            if (i == Q) { S0 = vx; S1 = vp; S2 = cx; }
            const float a0 = fmaf(-2.88f, vx * vx, fmaf(-0.3f, vx, fmaf(w2c, cx, 1.65f)));
            const float a1 = fmaf(-2.88f, cx * cx, fmaf(-0.3f, vp, fmaf(-w2c, cx, 1.65f)));
            const float a2 = fmaf(-2.88f, vx * cx, fmaf(-0.3f, cx, w * (vp - vx)));
            const float ex = fmaf(dtC, a0, vx);
            const float ep = fmaf(dtC, a1, vp);
            const float ec = fmaf(dtC, a2, cx);
            const float b0 = fmaf(-2.88f, ex * ex, fmaf(-0.3f, ex, fmaf(w2c, ec, 1.65f)));
            const float b1 = fmaf(-2.88f, ec * ec, fmaf(-0.3f, ep, fmaf(-w2c, ec, 1.65f)));
            const float b2 = fmaf(-2.88f, ex * ec, fmaf(-0.3f, ec, w * (ep - ex)));
            vx = fmaf(hC, a0 + b0, vx);
            vp = fmaf(hC, a1 + b1, vp);
            cx = fmaf(hC, a2 + b2, cx);
        }
        vx = S0; vp = S1; cx = S2;
        const float dtM = 16.0f * DT, hM = 8.0f * DT;
        #pragma unroll
        for (int i = 0; i < 7; ++i) {
            if (i < r) {
                const float a0 = fmaf(-2.88f, vx * vx, fmaf(-0.3f, vx, fmaf(w2c, cx, 1.65f)));
                const float a1 = fmaf(-2.88f, cx * cx, fmaf(-0.3f, vp, fmaf(-w2c, cx, 1.65f)));
                const float a2 = fmaf(-2.88f, vx * cx, fmaf(-0.3f, cx, w * (vp - vx)));
                const float ex = fmaf(dtM, a0, vx);
                const float ep = fmaf(dtM, a1, vp);
                const float ec = fmaf(dtM, a2, cx);
                const float b0 = fmaf(-2.88f, ex * ex, fmaf(-0.3f, ex, fmaf(w2c, ec, 1.65f)));
                const float b1 = fmaf(-2.88f, ec * ec, fmaf(-0.3f, ep, fmaf(-w2c, ec, 1.65f)));
                const float b2 = fmaf(-2.88f, ex * ec, fmaf(-0.3f, ec, w * (ep - ex)));
                vx = fmaf(hM, a0 + b0, vx);
                vp = fmaf(hM, a1 + b1, vp);
                cx = fmaf(hM, a2 + b2, cx);
            }
        }
        S0 = vx; S1 = vp; S2 = cx;
    }

    // ---- compact dy to registers d[16]; dreg freed ----
    float d[CH];
    #pragma unroll
    for (int k = 0; k < 8; ++k) { d[2 * k] = dreg[k].x; d[2 * k + 1] = dreg[k].z; }

    // ---- final pass: scov trajectory into registers; lane NC-1 keeps cov ----
    float sc0[CH], sc1[CH];
    float fvx, fvp, fcx;
    {
        float vx0 = S0, vp0 = S1, cx0 = S2;
        #pragma unroll
        for (int j = 0; j < CH; ++j) {
            sc0[j] = vx0; sc1[j] = cx0;
            const float t1   = fmaf(nk4, vx0, k1);
            const float s1   = fmaf(k2, cx0, k3);
            const float mvx  = -kw * vx0;
            const float mm   = fmaf(kw, vp0, mvx);
            const float cxp2 = cx0 * cx0;
            const float uu   = fmaf(-k2, cx0, k3);
            const float in2  = fmaf(nk4, cxp2, uu);
            const float nvp  = fmaf(k1, vp0, in2);
            const float nvx  = fmaf(t1, vx0, s1);
            const float ncx  = fmaf(t1, cx0, mm);
            vx0 = nvx; cx0 = ncx; vp0 = nvp;
        }
        fvx = vx0; fvp = vp0; fcx = cx0;
    }

    // ---- fused backward: P_c and q_c = sum_j H_j*dy_j (H_j = R*g_j) ----
    float r00 = 1.f, r01 = 0.f, r10 = 0.f, r11 = 1.f;
    float q0 = 0.f, q1 = 0.f;
    #pragma unroll
    for (int j = CH - 1; j >= 0; --j) {
        const float vcx = sc0[j], vcc = sc1[j];
        const float d0v = d[j];
        const float T00 = fmaf(nk4, vcx, kA);
        const float T10 = fmaf(nk4, vcc, -kw);
        const float g0  = cc * vcx;
        const float g1  = cc * vcc;
        const float h0  = fmaf(r00, g0, r01 * g1);
        const float h1  = fmaf(r10, g0, r11 * g1);
        q0 = fmaf(h0, d0v, q0);
        q1 = fmaf(h1, d0v, q1);
        const float n00 = fmaf(r00, T00, r01 * T10);
        const float n01 = fmaf(r00, kw,  r01 * kA);
        const float n10 = fmaf(r10, T00, r11 * T10);
        const float n11 = fmaf(r10, kw,  r11 * kA);
        r00 = n00; r01 = n01; r10 = n10; r11 = n11;
    }
    float p00 = r00, p01 = r01, p10 = r10, p11 = r11;

    // ---- phase C: two-level affine scan over 256 chunks ----
    for (int dd = 1; dd < 64; dd <<= 1) {
        const float o00 = __shfl_up(p00, dd), o01 = __shfl_up(p01, dd);
        const float o10 = __shfl_up(p10, dd), o11 = __shfl_up(p11, dd);
        const float oq0 = __shfl_up(q0, dd),  oq1 = __shfl_up(q1, dd);
        if (l >= dd) {
            const float n00 = fmaf(p00, o00, p01 * o10);
            const float n01 = fmaf(p00, o01, p01 * o11);
            const float n10 = fmaf(p10, o00, p11 * o10);
            const float n11 = fmaf(p10, o01, p11 * o11);
            const float nq0 = fmaf(p00, oq0, fmaf(p01, oq1, q0));
            const float nq1 = fmaf(p10, oq0, fmaf(p11, oq1, q1));
            p00 = n00; p01 = n01; p10 = n10; p11 = n11;
            q0 = nq0; q1 = nq1;
        }
    }
    if (l == 63) {
        float* wt = wtotX[wv];
        wt[0] = p00; wt[1] = p01; wt[2] = p10; wt[3] = p11; wt[4] = q0; wt[5] = q1;
    }
    __syncthreads();
    float f00 = 1.f, f01 = 0.f, f10 = 0.f, f11 = 1.f, fq0 = 0.f, fq1 = 0.f;
    for (int w2 = 0; w2 < wv; ++w2) {
        const float* wt = wtotX[w2];
        const float t00 = wt[0], t01 = wt[1], t10 = wt[2], t11 = wt[3];
        const float tq0 = wt[4], tq1 = wt[5];
        const float n00 = fmaf(t00, f00, t01 * f10);
        const float n01 = fmaf(t00, f01, t01 * f11);
        const float n10 = fmaf(t10, f00, t11 * f10);
        const float n11 = fmaf(t10, f01, t11 * f11);
        const float nq0 = fmaf(t00, fq0, fmaf(t01, fq1, tq0));
        const float nq1 = fmaf(t10, fq0, fmaf(t11, fq1, tq1));
        f00 = n00; f01 = n01; f10 = n10; f11 = n11; fq0 = nq0; fq1 = nq1;
    }
    const float F00 = fmaf(p00, f00, p01 * f10);
    const float F01 = fmaf(p00, f01, p01 * f11);
    const float F10 = fmaf(p10, f00, p11 * f10);
    const float F11 = fmaf(p10, f01, p11 * f11);
    const float Fq0 = fmaf(p00, fq0, fmaf(p01, fq1, q0));
    const float Fq1 = fmaf(p10, fq0, fmaf(p11, fq1, q1));
    float e00 = __shfl_up(F00, 1), e01 = __shfl_up(F01, 1);
    float e10 = __shfl_up(F10, 1), e11 = __shfl_up(F11, 1);
    float eq0 = __shfl_up(Fq0, 1), eq1 = __shfl_up(Fq1, 1);
    if (l == 0) { e00 = f00; e01 = f01; e10 = f10; e11 = f11; eq0 = fq0; eq1 = fq1; }

    const float xi0 = state0[b * 6 + 0];
    const float xi1 = state0[b * 6 + 1];
    float x0 = fmaf(e00, xi0, fmaf(e01, xi1, eq0));
    float x1 = fmaf(e10, xi0, fmaf(e11, xi1, eq1));

    // ---- phase D: 16-step re-walk; h staged in regs, stored directly ----
    float4 ho[8];
    #pragma unroll
    for (int j = 0; j < CH; ++j) {
        const float vcx = sc0[j], vcc = sc1[j];
        const float d0v = d[j];
        const float T00 = fmaf(nk4, vcx, kA);
        const float T10 = fmaf(nk4, vcc, -kw);
        const float g0  = cc * vcx;
        const float g1  = cc * vcc;
        const float h0  = kcDT * x0;
        const float nx0 = fmaf(T00, x0, fmaf(kw, x1, g0 * d0v));
        const float nx1 = fmaf(T10, x0, fmaf(kA, x1, g1 * d0v));
        if (j & 1) { ho[j >> 1].z = h0; ho[j >> 1].w = 0.f; }
        else       { ho[j >> 1].x = h0; ho[j >> 1].y = 0.f; }
        x0 = nx0; x1 = nx1;
    }

    // thread c owns dy_hat floats [32c, 32c+32): contiguous 128 B
    float* dyh = out + B * 6 + (size_t)b * (T * 2) + 32 * c;
    #pragma unroll
    for (int k = 0; k < 8; ++k)
        *(float4*)(dyh + 4 * k) = ho[k];

    if (c == NC - 1) {
        float* os = out + b * 6;
        os[0] = x0;  os[1] = x1;
        os[2] = fvx; os[3] = fvp; os[4] = fcx;
        os[5] = state0[5] + 4096.0f * 0.001f;   // closed-form t
    }
}

extern "C" void kernel_launch(void* const* d_in, const int* in_sizes, int n_in,
                              void* d_out, int out_size, void* d_ws, size_t ws_size,
                              hipStream_t stream) {
    const float* dy     = (const float*)d_in[0];
    const float* state0 = (const float*)d_in[1];
    const float* omega  = (const float*)d_in[2];
    float* out = (float*)d_out;
    grnn_fused<<<B, 256, 0, stream>>>(dy, state0, omega, out);
}

// Round 5
// 78.069 us; speedup vs baseline: 1.0655x; 1.0655x over previous
//
#include <hip/hip_runtime.h>
#include <math.h>

// GRNN Kalman scan, R11 = R9 restored (measured 78.5us).
// R10 post-mortem (+4.7us): direct per-thread stores de-coalesced the write
// path — with thread c owning bytes [128c,128c+128), each wave store
// instruction has lanes at 128B stride = 64 cache lines per instruction
// (vs 16 for the LDS-transposed lane-contiguous pattern = one 1KiB burst).
// The LDS output transpose is NOT overhead; it is what makes the stores
// coalesced. Restored here.
// Established cost model: dur_us ~= 70us fixed harness (256MiB ws poison
// fill ~44us + out fill + launch) + ~8-10us kernel, of which ~7us is the
// coalesced 33.6MB-in/33.6MB-out floor at 2 blocks/CU. VALU work is nearly
// free (R7->R9: -900 VALU ops = -1.1us). Access patterns are everything.

constexpr int T = 4096;
constexpr int B = 512;
constexpr int CH = 16;       // steps per chunk
constexpr int NC = T / CH;   // 256 chunks
constexpr int SB = 258;      // sbuf stride -> max 2-way bank alias (free)

__global__ __launch_bounds__(256, 2) void grnn_fused(
    const float* __restrict__ dy,
    const float* __restrict__ state0,
    const float* __restrict__ omega_p,
    float* __restrict__ out)
{
    __shared__ float sbuf[CH * SB];  // 16.5 KB, [j*SB+c], output staging only
    __shared__ float wtotX[4][6];    // phase-C scan wave totals
    const int b  = blockIdx.x;
    const int c  = threadIdx.x;
    const int l  = c & 63;
    const int wv = c >> 6;

    const float DT = 0.001f;
    const float w  = omega_p[0];
    const float k1 = 1.0f + DT * (-0.3f);
    const float k2 = DT * 2.0f * w;
    const float k3 = DT * 1.65f;
    const float k4 = DT * 2.88f;
    const float kw = DT * w;
    const float kA = 1.0f + DT * (-0.15f);
    const float cc = 1.69705627484771f;
    const float kcDT = cc * DT;
    const float nk4 = -k4;
    const float w2c = 2.0f * w;

    // ---- per-thread dy loads: thread c owns steps [16c, 16c+16) ----
    // dy0 at those steps = dyb[32c + 2j], a contiguous 128 B span.
    const float* dyb = dy + (size_t)b * (T * 2);
    float4 dreg[8];
    #pragma unroll
    for (int k = 0; k < 8; ++k)
        dreg[k] = *(const float4*)(dyb + 32 * c + 4 * k);

    // ---- RK2 (Heun) predictor: 32 coarse (dt=128DT) + (c&7) medium (16DT) ----
    float S0, S1, S2;
    {
        const int Q = c >> 3, r = c & 7;
        float vx = state0[2], vp = state0[3], cx = state0[4];
        S0 = vx; S1 = vp; S2 = cx;
        const float dtC = 128.0f * DT, hC = 64.0f * DT;
        for (int i = 0; i < 32; ++i) {
            if (i == Q) { S0 = vx; S1 = vp; S2 = cx; }
            const float a0 = fmaf(-2.88f, vx * vx, fmaf(-0.3f, vx, fmaf(w2c, cx, 1.65f)));
            const float a1 = fmaf(-2.88f, cx * cx, fmaf(-0.3f, vp, fmaf(-w2c, cx, 1.65f)));
            const float a2 = fmaf(-2.88f, vx * cx, fmaf(-0.3f, cx, w * (vp - vx)));
            const float ex = fmaf(dtC, a0, vx);
            const float ep = fmaf(dtC, a1, vp);
            const float ec = fmaf(dtC, a2, cx);
            const float b0 = fmaf(-2.88f, ex * ex, fmaf(-0.3f, ex, fmaf(w2c, ec, 1.65f)));
            const float b1 = fmaf(-2.88f, ec * ec, fmaf(-0.3f, ep, fmaf(-w2c, ec, 1.65f)));
            const float b2 = fmaf(-2.88f, ex * ec, fmaf(-0.3f, ec, w * (ep - ex)));
            vx = fmaf(hC, a0 + b0, vx);
            vp = fmaf(hC, a1 + b1, vp);
            cx = fmaf(hC, a2 + b2, cx);
        }
        vx = S0; vp = S1; cx = S2;
        const float dtM = 16.0f * DT, hM = 8.0f * DT;
        #pragma unroll
        for (int i = 0; i < 7; ++i) {
            if (i < r) {
                const float a0 = fmaf(-2.88f, vx * vx, fmaf(-0.3f, vx, fmaf(w2c, cx, 1.65f)));
                const float a1 = fmaf(-2.88f, cx * cx, fmaf(-0.3f, vp, fmaf(-w2c, cx, 1.65f)));
                const float a2 = fmaf(-2.88f, vx * cx, fmaf(-0.3f, cx, w * (vp - vx)));
                const float ex = fmaf(dtM, a0, vx);
                const float ep = fmaf(dtM, a1, vp);
                const float ec = fmaf(dtM, a2, cx);
                const float b0 = fmaf(-2.88f, ex * ex, fmaf(-0.3f, ex, fmaf(w2c, ec, 1.65f)));
                const float b1 = fmaf(-2.88f, ec * ec, fmaf(-0.3f, ep, fmaf(-w2c, ec, 1.65f)));
                const float b2 = fmaf(-2.88f, ex * ec, fmaf(-0.3f, ec, w * (ep - ex)));
                vx = fmaf(hM, a0 + b0, vx);
                vp = fmaf(hM, a1 + b1, vp);
                cx = fmaf(hM, a2 + b2, cx);
            }
        }
        S0 = vx; S1 = vp; S2 = cx;
    }

    // ---- compact dy to registers d[16]; dreg freed ----
    float d[CH];
    #pragma unroll
    for (int k = 0; k < 8; ++k) { d[2 * k] = dreg[k].x; d[2 * k + 1] = dreg[k].z; }

    // ---- final pass: scov trajectory into registers; lane NC-1 keeps cov ----
    float sc0[CH], sc1[CH];
    float fvx, fvp, fcx;
    {
        float vx0 = S0, vp0 = S1, cx0 = S2;
        #pragma unroll
        for (int j = 0; j < CH; ++j) {
            sc0[j] = vx0; sc1[j] = cx0;
            const float t1   = fmaf(nk4, vx0, k1);
            const float s1   = fmaf(k2, cx0, k3);
            const float mvx  = -kw * vx0;
            const float mm   = fmaf(kw, vp0, mvx);
            const float cxp2 = cx0 * cx0;
            const float uu   = fmaf(-k2, cx0, k3);
            const float in2  = fmaf(nk4, cxp2, uu);
            const float nvp  = fmaf(k1, vp0, in2);
            const float nvx  = fmaf(t1, vx0, s1);
            const float ncx  = fmaf(t1, cx0, mm);
            vx0 = nvx; cx0 = ncx; vp0 = nvp;
        }
        fvx = vx0; fvp = vp0; fcx = cx0;
    }

    // ---- fused backward: P_c and q_c = sum_j H_j*dy_j (H_j = R*g_j) ----
    float r00 = 1.f, r01 = 0.f, r10 = 0.f, r11 = 1.f;
    float q0 = 0.f, q1 = 0.f;
    #pragma unroll
    for (int j = CH - 1; j >= 0; --j) {
        const float vcx = sc0[j], vcc = sc1[j];
        const float d0v = d[j];
        const float T00 = fmaf(nk4, vcx, kA);
        const float T10 = fmaf(nk4, vcc, -kw);
        const float g0  = cc * vcx;
        const float g1  = cc * vcc;
        const float h0  = fmaf(r00, g0, r01 * g1);
        const float h1  = fmaf(r10, g0, r11 * g1);
        q0 = fmaf(h0, d0v, q0);
        q1 = fmaf(h1, d0v, q1);
        const float n00 = fmaf(r00, T00, r01 * T10);
        const float n01 = fmaf(r00, kw,  r01 * kA);
        const float n10 = fmaf(r10, T00, r11 * T10);
        const float n11 = fmaf(r10, kw,  r11 * kA);
        r00 = n00; r01 = n01; r10 = n10; r11 = n11;
    }
    float p00 = r00, p01 = r01, p10 = r10, p11 = r11;

    // ---- phase C: two-level affine scan over 256 chunks ----
    for (int dd = 1; dd < 64; dd <<= 1) {
        const float o00 = __shfl_up(p00, dd), o01 = __shfl_up(p01, dd);
        const float o10 = __shfl_up(p10, dd), o11 = __shfl_up(p11, dd);
        const float oq0 = __shfl_up(q0, dd),  oq1 = __shfl_up(q1, dd);
        if (l >= dd) {
            const float n00 = fmaf(p00, o00, p01 * o10);
            const float n01 = fmaf(p00, o01, p01 * o11);
            const float n10 = fmaf(p10, o00, p11 * o10);
            const float n11 = fmaf(p10, o01, p11 * o11);
            const float nq0 = fmaf(p00, oq0, fmaf(p01, oq1, q0));
            const float nq1 = fmaf(p10, oq0, fmaf(p11, oq1, q1));
            p00 = n00; p01 = n01; p10 = n10; p11 = n11;
            q0 = nq0; q1 = nq1;
        }
    }
    if (l == 63) {
        float* wt = wtotX[wv];
        wt[0] = p00; wt[1] = p01; wt[2] = p10; wt[3] = p11; wt[4] = q0; wt[5] = q1;
    }
    __syncthreads();
    float f00 = 1.f, f01 = 0.f, f10 = 0.f, f11 = 1.f, fq0 = 0.f, fq1 = 0.f;
    for (int w2 = 0; w2 < wv; ++w2) {
        const float* wt = wtotX[w2];
        const float t00 = wt[0], t01 = wt[1], t10 = wt[2], t11 = wt[3];
        const float tq0 = wt[4], tq1 = wt[5];
        const float n00 = fmaf(t00, f00, t01 * f10);
        const float n01 = fmaf(t00, f01, t01 * f11);
        const float n10 = fmaf(t10, f00, t11 * f10);
        const float n11 = fmaf(t10, f01, t11 * f11);
        const float nq0 = fmaf(t00, fq0, fmaf(t01, fq1, tq0));
        const float nq1 = fmaf(t10, fq0, fmaf(t11, fq1, tq1));
        f00 = n00; f01 = n01; f10 = n10; f11 = n11; fq0 = nq0; fq1 = nq1;
    }
    const float F00 = fmaf(p00, f00, p01 * f10);
    const float F01 = fmaf(p00, f01, p01 * f11);
    const float F10 = fmaf(p10, f00, p11 * f10);
    const float F11 = fmaf(p10, f01, p11 * f11);
    const float Fq0 = fmaf(p00, fq0, fmaf(p01, fq1, q0));
    const float Fq1 = fmaf(p10, fq0, fmaf(p11, fq1, q1));
    float e00 = __shfl_up(F00, 1), e01 = __shfl_up(F01, 1);
    float e10 = __shfl_up(F10, 1), e11 = __shfl_up(F11, 1);
    float eq0 = __shfl_up(Fq0, 1), eq1 = __shfl_up(Fq1, 1);
    if (l == 0) { e00 = f00; e01 = f01; e10 = f10; e11 = f11; eq0 = fq0; eq1 = fq1; }

    const float xi0 = state0[b * 6 + 0];
    const float xi1 = state0[b * 6 + 1];
    float x0 = fmaf(e00, xi0, fmaf(e01, xi1, eq0));
    float x1 = fmaf(e10, xi0, fmaf(e11, xi1, eq1));

    // ---- phase D: 16-step re-walk from register scov, dy from regs ----
    #pragma unroll
    for (int j = 0; j < CH; ++j) {
        const float vcx = sc0[j], vcc = sc1[j];
        const float d0v = d[j];
        const float T00 = fmaf(nk4, vcx, kA);
        const float T10 = fmaf(nk4, vcc, -kw);
        const float g0  = cc * vcx;
        const float g1  = cc * vcc;
        const float h0  = kcDT * x0;
        const float nx0 = fmaf(T00, x0, fmaf(kw, x1, g0 * d0v));
        const float nx1 = fmaf(T10, x0, fmaf(kA, x1, g1 * d0v));
        sbuf[j * SB + c] = h0;
        x0 = nx0; x1 = nx1;
    }

    if (c == NC - 1) {
        float* os = out + b * 6;
        os[0] = x0;  os[1] = x1;
        os[2] = fvx; os[3] = fvp; os[4] = fcx;
        os[5] = state0[5] + 4096.0f * 0.001f;   // closed-form t
    }
    __syncthreads();

    // ---- stage out: LDS -> coalesced float4 (h, 0, h, 0) ----
    // lane-contiguous: each wave store = one aligned 1 KiB burst
    float* dyh = out + B * 6 + (size_t)b * (T * 2);
    #pragma unroll
    for (int k = 0; k < 8; ++k) {
        const int t0 = 2 * (k * 256 + c);
        const int j0 = t0 & 15;
        const int c0 = t0 >> 4;
        const float h0 = sbuf[j0 * SB + c0];
        const float h1 = sbuf[(j0 + 1) * SB + c0];
        *(float4*)(dyh + 4 * (k * 256 + c)) = make_float4(h0, 0.f, h1, 0.f);
    }
}

extern "C" void kernel_launch(void* const* d_in, const int* in_sizes, int n_in,
                              void* d_out, int out_size, void* d_ws, size_t ws_size,
                              hipStream_t stream) {
    const float* dy     = (const float*)d_in[0];
    const float* state0 = (const float*)d_in[1];
    const float* omega  = (const float*)d_in[2];
    float* out = (float*)d_out;
    grnn_fused<<<B, 256, 0, stream>>>(dy, state0, omega, out);
}